// Round 8
// baseline (105.066 us; speedup 1.0000x reference)
//
#include <hip/hip_runtime.h>
#include <hip/hip_bf16.h>

// Problem constants: B=256, LATENT=256, N=64, EMB=64, NBOND=5
// Dtypes (established R2-R4): ALL float tensors fp32 (inputs AND output),
// nra int32. Threshold 20.0 -> bf16 internals are free precision-wise.
// Timing note (R6/R7): ~50-55 us of dur_us is fixed harness overhead
// (0xAA re-poison of 256 MiB d_ws at ~42 us + d_out fill + restores + gaps).
#define HUGEF 1000.0f

typedef __hip_bfloat16 bf16;
typedef __attribute__((ext_vector_type(8))) short short8;   // MFMA A/B frag (8 bf16)
typedef __attribute__((ext_vector_type(4))) float floatx4;  // MFMA C/D frag
typedef __attribute__((ext_vector_type(2))) float float2v;  // v_pk_* pair

__device__ __forceinline__ ushort f2bf(float x) {
    return __bfloat16_as_ushort(__float2bfloat16(x));
}
__device__ __forceinline__ float b2f(bf16 x) { return __bfloat162float(x); }
__device__ __forceinline__ float2v relu2(float2v x) {
    float2v r; r.x = fmaxf(x.x, 0.f); r.y = fmaxf(x.y, 0.f); return r;
}
__device__ __forceinline__ float2v mk2(float x, float y) {
    float2v r; r.x = x; r.y = y; return r;
}

// -------------------------------------------------------------------------
// Kernel 1 (R8): h = z@Wn + bn ; a' = h@W1a + b1 ; c = h@W1b  (full MFMA)
// R8: m-tile 64 -> 32, grid (64,8) = 512 blocks = 2 blocks/CU so one
// block's MFMA overlaps the other's global staging (R7 had 1 block/CU,
// staging latency fully barrier-exposed). LDS ~49 KB -> 2 blocks fit.
// Wave wv: m-16-tile (wv>>1), n/f-16-tile pair base (wv&1)*2.
// -------------------------------------------------------------------------
__global__ __launch_bounds__(256, 2) void k_hac(
    const float* __restrict__ z, const float* __restrict__ Wn,
    const float* __restrict__ bn, const float* __restrict__ W1,
    const float* __restrict__ b1, bf16* __restrict__ a_ws,
    bf16* __restrict__ c_ws)
{
    __shared__ ushort zt[32][136];   // z-tile  [m][k0..127] bf16 (8.7 KB)
    __shared__ ushort wnt[64][136];  // Wn-tile [n][k0..127] bf16 (17.4 KB)
    __shared__ ushort ht[32][72];    // h       [m][e] bf16 (4.6 KB)
    __shared__ ushort w1at[64][72];  // W1a^T   [f][e] bf16 (9.2 KB)
    __shared__ ushort w1bt[64][72];  // W1b^T   [f][e] bf16 (9.2 KB)

    const int t = threadIdx.x;
    const int lane = t & 63;
    const int wv = t >> 6;          // wave 0..3
    const int l15 = lane & 15;
    const int quad = lane >> 4;     // 0..3
    const int atom = blockIdx.x;
    const int m0 = blockIdx.y * 32;
    const int n0 = atom * 64;
    const int mrow = (wv >> 1) * 16;     // this wave's m-16-tile base
    const int ntb = (wv & 1) * 2;        // this wave's n/f-16-tile pair base

    {   // stage W1a/W1b transposed [f][e] (coalesced across f)
        const int f = t & 63;
        const int g = t >> 6;
        #pragma unroll
        for (int qq = 0; qq < 4; ++qq) {
            int e = g * 16 + qq * 4;
            ushort4 va, vb;
            va.x = f2bf(W1[(e + 0) * 64 + f]);
            va.y = f2bf(W1[(e + 1) * 64 + f]);
            va.z = f2bf(W1[(e + 2) * 64 + f]);
            va.w = f2bf(W1[(e + 3) * 64 + f]);
            vb.x = f2bf(W1[(64 + e + 0) * 64 + f]);
            vb.y = f2bf(W1[(64 + e + 1) * 64 + f]);
            vb.z = f2bf(W1[(64 + e + 2) * 64 + f]);
            vb.w = f2bf(W1[(64 + e + 3) * 64 + f]);
            *(ushort4*)&w1at[f][e] = va;
            *(ushort4*)&w1bt[f][e] = vb;
        }
    }

    // ---- stage 1: z @ Wn over K=256 in two 128-wide LDS tiles ----
    floatx4 acc1[2] = {};
    for (int kt = 0; kt < 256; kt += 128) {
        __syncthreads();
        #pragma unroll
        for (int r = 0; r < 4; ++r) {             // zt[m][kk] <- z (coalesced f4)
            int q = t + 256 * r;                  // 1024 float4 of 32x128
            int m = q >> 5, kk = (q & 31) * 4;
            float4 v = *(const float4*)&z[(m0 + m) * 256 + kt + kk];
            ushort4 u = {f2bf(v.x), f2bf(v.y), f2bf(v.z), f2bf(v.w)};
            *(ushort4*)&zt[m][kk] = u;
        }
        {                                          // wnt[n][k] <- Wn^T gather
            int n = t & 63, g = t >> 6;
            #pragma unroll
            for (int qq = 0; qq < 8; ++qq) {
                int k = g * 32 + qq * 4;
                const float* p = &Wn[(size_t)(kt + k) * 4096 + n0 + n];
                ushort4 u = {f2bf(p[0]), f2bf(p[4096]),
                             f2bf(p[2 * 4096]), f2bf(p[3 * 4096])};
                *(ushort4*)&wnt[n][k] = u;
            }
        }
        __syncthreads();
        #pragma unroll
        for (int ks = 0; ks < 4; ++ks) {           // 4 K=32 MFMA steps
            short8 a = *(const short8*)&zt[mrow + l15][ks * 32 + quad * 8];
            #pragma unroll
            for (int p = 0; p < 2; ++p) {
                short8 bf = *(const short8*)&wnt[(ntb + p) * 16 + l15][ks * 32 + quad * 8];
                acc1[p] = __builtin_amdgcn_mfma_f32_16x16x32_bf16(a, bf, acc1[p], 0, 0, 0);
            }
        }
    }

    // ---- h (+bn) -> ht [m][e] ----
    #pragma unroll
    for (int p = 0; p < 2; ++p) {
        float bnv = bn[n0 + (ntb + p) * 16 + l15];
        #pragma unroll
        for (int r = 0; r < 4; ++r)
            ht[mrow + quad * 4 + r][(ntb + p) * 16 + l15] = f2bf(acc1[p][r] + bnv);
    }
    __syncthreads();

    // ---- stage 2: h @ W1a, h @ W1b (K=64, 2 MFMA steps) ----
    floatx4 acc2a[2] = {}, acc2c[2] = {};
    #pragma unroll
    for (int ks = 0; ks < 2; ++ks) {
        short8 a = *(const short8*)&ht[mrow + l15][ks * 32 + quad * 8];
        #pragma unroll
        for (int p = 0; p < 2; ++p) {
            short8 ba = *(const short8*)&w1at[(ntb + p) * 16 + l15][ks * 32 + quad * 8];
            short8 bb = *(const short8*)&w1bt[(ntb + p) * 16 + l15][ks * 32 + quad * 8];
            acc2a[p] = __builtin_amdgcn_mfma_f32_16x16x32_bf16(a, ba, acc2a[p], 0, 0, 0);
            acc2c[p] = __builtin_amdgcn_mfma_f32_16x16x32_bf16(a, bb, acc2c[p], 0, 0, 0);
        }
    }

    // ---- epilogue ----
    #pragma unroll
    for (int p = 0; p < 2; ++p) {
        float b1v = b1[(ntb + p) * 16 + l15];
        #pragma unroll
        for (int r = 0; r < 4; ++r) {
            int m = mrow + quad * 4 + r;
            size_t idx = (size_t)(m0 + m) * 4096 + n0 + (ntb + p) * 16 + l15;
            a_ws[idx] = __float2bfloat16(acc2a[p][r] + b1v);
            c_ws[idx] = __float2bfloat16(acc2c[p][r]);
        }
    }
}

// -------------------------------------------------------------------------
// Kernel 2 (R8): pairwise relu + W2 contraction + mask + symmetrize.
// Grid 256 = one block per batch (halves a/c staging vs R7's grid 512 and
// halves worst-case CU load). Wave wv owns row-octets {wv, wv+4}; each
// octet is fill-only (i0 >= n, store-only path) or the R7 packed-math
// compute path (v_pk_add/v_pk_fma on float2).
// -------------------------------------------------------------------------
__global__ __launch_bounds__(256) void k_pairs(
    const bf16* __restrict__ a_ws, const bf16* __restrict__ c_ws,
    const int* __restrict__ nra, const float* __restrict__ W2,
    const float* __restrict__ b2, float* __restrict__ out)
{
    __shared__ __align__(16) float as[64][68];
    __shared__ __align__(16) float cs[64][68];
    __shared__ __align__(16) float w2t[5][68];

    const int t = threadIdx.x;
    const int b = blockIdx.x;
    const int n = nra[b];

    #pragma unroll
    for (int r = 0; r < 4; ++r) {                 // bf16 ws -> fp32 LDS
        int q = t + 256 * r;
        int atom = q >> 4, ff = (q & 15) * 4;
        ushort4 av = *(const ushort4*)((const ushort*)a_ws + (size_t)b * 4096 + 4 * q);
        ushort4 cv = *(const ushort4*)((const ushort*)c_ws + (size_t)b * 4096 + 4 * q);
        as[atom][ff + 0] = b2f(__ushort_as_bfloat16(av.x));
        as[atom][ff + 1] = b2f(__ushort_as_bfloat16(av.y));
        as[atom][ff + 2] = b2f(__ushort_as_bfloat16(av.z));
        as[atom][ff + 3] = b2f(__ushort_as_bfloat16(av.w));
        cs[atom][ff + 0] = b2f(__ushort_as_bfloat16(cv.x));
        cs[atom][ff + 1] = b2f(__ushort_as_bfloat16(cv.y));
        cs[atom][ff + 2] = b2f(__ushort_as_bfloat16(cv.z));
        cs[atom][ff + 3] = b2f(__ushort_as_bfloat16(cv.w));
    }
    if (t < 64) {
        #pragma unroll
        for (int k = 0; k < 5; ++k) w2t[k][t] = W2[t * 5 + k];
    }
    float b2v[5];
    #pragma unroll
    for (int k = 0; k < 5; ++k) b2v[k] = b2[k];
    __syncthreads();

    const int j = t & 63;
    const int wv = t >> 6;
    const float fillv[5] = {-HUGEF, -HUGEF, -HUGEF, -HUGEF, HUGEF};

    #pragma unroll 1
    for (int oo = 0; oo < 2; ++oo) {
        const int i0 = (wv + 4 * oo) * 8;         // this wave's octet base
        if (i0 >= n) {                             // fill-only octet
            #pragma unroll
            for (int r = 0; r < 8; ++r) {
                float* op = out + ((size_t)(b * 64 + i0 + r) * 64 + j) * 5;
                #pragma unroll
                for (int k = 0; k < 5; ++k) op[k] = fillv[k];
            }
            continue;
        }

        float2v acc2[8][5] = {};
        for (int w8 = 0; w8 < 8; ++w8) {           // 8 f per iter
            const int f0 = w8 * 8;
            float4 ajA = *(const float4*)&as[j][f0];
            float4 ajB = *(const float4*)&as[j][f0 + 4];
            float4 cjA = *(const float4*)&cs[j][f0];
            float4 cjB = *(const float4*)&cs[j][f0 + 4];
            float2v aj0 = mk2(ajA.x, ajA.y), aj1 = mk2(ajA.z, ajA.w);
            float2v aj2 = mk2(ajB.x, ajB.y), aj3 = mk2(ajB.z, ajB.w);
            float2v cj0 = mk2(cjA.x, cjA.y), cj1 = mk2(cjA.z, cjA.w);
            float2v cj2 = mk2(cjB.x, cjB.y), cj3 = mk2(cjB.z, cjB.w);
            float2v w[5][4];
            #pragma unroll
            for (int k = 0; k < 5; ++k) {
                float4 wA = *(const float4*)&w2t[k][f0];
                float4 wB = *(const float4*)&w2t[k][f0 + 4];
                w[k][0] = mk2(wA.x, wA.y); w[k][1] = mk2(wA.z, wA.w);
                w[k][2] = mk2(wB.x, wB.y); w[k][3] = mk2(wB.z, wB.w);
            }
            #pragma unroll
            for (int r = 0; r < 8; ++r) {
                float4 aiA = *(const float4*)&as[i0 + r][f0];     // broadcast
                float4 aiB = *(const float4*)&as[i0 + r][f0 + 4];
                float4 ciA = *(const float4*)&cs[i0 + r][f0];
                float4 ciB = *(const float4*)&cs[i0 + r][f0 + 4];
                float2v s0 = relu2(mk2(aiA.x, aiA.y) + cj0) + relu2(aj0 + mk2(ciA.x, ciA.y));
                float2v s1 = relu2(mk2(aiA.z, aiA.w) + cj1) + relu2(aj1 + mk2(ciA.z, ciA.w));
                float2v s2 = relu2(mk2(aiB.x, aiB.y) + cj2) + relu2(aj2 + mk2(ciB.x, ciB.y));
                float2v s3 = relu2(mk2(aiB.z, aiB.w) + cj3) + relu2(aj3 + mk2(ciB.z, ciB.w));
                #pragma unroll
                for (int k = 0; k < 5; ++k)
                    acc2[r][k] += s0 * w[k][0] + s1 * w[k][1] +
                                  s2 * w[k][2] + s3 * w[k][3];
            }
        }

        #pragma unroll
        for (int r = 0; r < 8; ++r) {
            const int i = i0 + r;
            float* op = out + ((size_t)(b * 64 + i) * 64 + j) * 5;
            if (i >= n) {
                #pragma unroll
                for (int k = 0; k < 5; ++k) op[k] = fillv[k];
            } else {
                const bool masked = (j == i) || (j >= n);
                #pragma unroll
                for (int k = 0; k < 5; ++k) {
                    float v = masked ? fillv[k]
                                     : (0.5f * (acc2[r][k].x + acc2[r][k].y) + b2v[k]);
                    op[k] = v;
                }
            }
        }
    }
}

extern "C" void kernel_launch(void* const* d_in, const int* in_sizes, int n_in,
                              void* d_out, int out_size, void* d_ws, size_t ws_size,
                              hipStream_t stream)
{
    const float* z  = (const float*)d_in[0];   // (256, 256) fp32
    const int*   nra = (const int*)d_in[1];    // (256,) int32
    const float* Wn = (const float*)d_in[2];   // (256, 4096) fp32
    const float* bn = (const float*)d_in[3];   // (4096,) fp32
    const float* W1 = (const float*)d_in[4];   // (128, 64) fp32
    const float* b1 = (const float*)d_in[5];   // (64,) fp32
    const float* W2 = (const float*)d_in[6];   // (64, 5) fp32
    const float* b2 = (const float*)d_in[7];   // (5,) fp32
    float* out = (float*)d_out;                // (256, 64, 64, 5) fp32

    bf16* a_ws = (bf16*)d_ws;                  // 256*4096 bf16 (a' = a + b1)
    bf16* c_ws = a_ws + 256 * 4096;            // 256*4096 bf16

    hipLaunchKernelGGL(k_hac, dim3(64, 8), dim3(256), 0, stream,
                       z, Wn, bn, W1, b1, a_ws, c_ws);
    hipLaunchKernelGGL(k_pairs, dim3(256), dim3(256), 0, stream,
                       a_ws, c_ws, nra, W2, b2, out);
}

// Round 9
// 100.805 us; speedup vs baseline: 1.0423x; 1.0423x over previous
//
#include <hip/hip_runtime.h>
#include <hip/hip_bf16.h>

// Problem constants: B=256, LATENT=256, N=64, EMB=64, NBOND=5
// Dtypes (established R2-R4): ALL float tensors fp32 (inputs AND output),
// nra int32. Threshold 20.0 -> bf16 internals are free precision-wise.
// Timing note (R6-R8): ~46 us of dur_us is harness poison-fill (256 MiB d_ws
// at ~42 us, 80% HBM peak + 21 MB d_out) plus restores/dispatch gaps; the two
// kernels are ~6-8 us combined. R8's distribution changes regressed the
// block-level makespan (see journal) -> this is the exact R7 configuration.
#define HUGEF 1000.0f

typedef __hip_bfloat16 bf16;
typedef __attribute__((ext_vector_type(8))) short short8;   // MFMA A/B frag (8 bf16)
typedef __attribute__((ext_vector_type(4))) float floatx4;  // MFMA C/D frag
typedef __attribute__((ext_vector_type(2))) float float2v;  // v_pk_* pair

__device__ __forceinline__ ushort f2bf(float x) {
    return __bfloat16_as_ushort(__float2bfloat16(x));
}
__device__ __forceinline__ float b2f(bf16 x) { return __bfloat162float(x); }
__device__ __forceinline__ float2v relu2(float2v x) {
    float2v r; r.x = fmaxf(x.x, 0.f); r.y = fmaxf(x.y, 0.f); return r;
}
__device__ __forceinline__ float2v mk2(float x, float y) {
    float2v r; r.x = x; r.y = y; return r;
}

// -------------------------------------------------------------------------
// Kernel 1 (R7 config, known good):
//   h = z@Wn + bn ; a' = h@W1a + b1 ; c = h@W1b   (full MFMA, bf16 internals)
// Block = (atom, 64-batch tile), grid (64,4), 256 thr = 4 waves, 1 block/CU.
// Each atom's Wn tile and W1 transpose staged exactly once (R8 halved the
// m-tile and doubled this staging -> regression; do not re-split).
// -------------------------------------------------------------------------
__global__ __launch_bounds__(256) void k_hac(
    const float* __restrict__ z, const float* __restrict__ Wn,
    const float* __restrict__ bn, const float* __restrict__ W1,
    const float* __restrict__ b1, bf16* __restrict__ a_ws,
    bf16* __restrict__ c_ws)
{
    __shared__ ushort zt[64][136];   // z-tile  [m][k0..127] bf16
    __shared__ ushort wnt[64][136];  // Wn-tile [n][k0..127] bf16
    __shared__ ushort ht[64][72];    // h       [m][e] bf16
    __shared__ ushort w1at[64][72];  // W1a^T   [f][e] bf16
    __shared__ ushort w1bt[64][72];  // W1b^T   [f][e] bf16

    const int t = threadIdx.x;
    const int lane = t & 63;
    const int wv = t >> 6;
    const int l15 = lane & 15;
    const int quad = lane >> 4;
    const int atom = blockIdx.x;
    const int m0 = blockIdx.y * 64;
    const int n0 = atom * 64;

    {   // stage W1a/W1b transposed
        const int f = t & 63;
        const int g = t >> 6;
        #pragma unroll
        for (int qq = 0; qq < 4; ++qq) {
            int e = g * 16 + qq * 4;
            ushort4 va, vb;
            va.x = f2bf(W1[(e + 0) * 64 + f]);
            va.y = f2bf(W1[(e + 1) * 64 + f]);
            va.z = f2bf(W1[(e + 2) * 64 + f]);
            va.w = f2bf(W1[(e + 3) * 64 + f]);
            vb.x = f2bf(W1[(64 + e + 0) * 64 + f]);
            vb.y = f2bf(W1[(64 + e + 1) * 64 + f]);
            vb.z = f2bf(W1[(64 + e + 2) * 64 + f]);
            vb.w = f2bf(W1[(64 + e + 3) * 64 + f]);
            *(ushort4*)&w1at[f][e] = va;
            *(ushort4*)&w1bt[f][e] = vb;
        }
    }

    floatx4 acc1[4] = {};
    for (int kt = 0; kt < 256; kt += 128) {
        __syncthreads();
        #pragma unroll
        for (int r = 0; r < 8; ++r) {             // zt <- z (coalesced f4)
            int q = t + 256 * r;
            int m = q >> 5, kk = (q & 31) * 4;
            float4 v = *(const float4*)&z[(m0 + m) * 256 + kt + kk];
            ushort4 u = {f2bf(v.x), f2bf(v.y), f2bf(v.z), f2bf(v.w)};
            *(ushort4*)&zt[m][kk] = u;
        }
        {                                          // wnt[n][k] <- Wn^T gather
            int n = t & 63, g = t >> 6;
            #pragma unroll
            for (int qq = 0; qq < 8; ++qq) {
                int k = g * 32 + qq * 4;
                const float* p = &Wn[(size_t)(kt + k) * 4096 + n0 + n];
                ushort4 u = {f2bf(p[0]), f2bf(p[4096]),
                             f2bf(p[2 * 4096]), f2bf(p[3 * 4096])};
                *(ushort4*)&wnt[n][k] = u;
            }
        }
        __syncthreads();
        #pragma unroll
        for (int ks = 0; ks < 4; ++ks) {
            short8 a = *(const short8*)&zt[wv * 16 + l15][ks * 32 + quad * 8];
            #pragma unroll
            for (int nt = 0; nt < 4; ++nt) {
                short8 bf = *(const short8*)&wnt[nt * 16 + l15][ks * 32 + quad * 8];
                acc1[nt] = __builtin_amdgcn_mfma_f32_16x16x32_bf16(a, bf, acc1[nt], 0, 0, 0);
            }
        }
    }

    #pragma unroll
    for (int nt = 0; nt < 4; ++nt) {              // h (+bn) -> ht [m][e]
        float bnv = bn[n0 + nt * 16 + l15];
        #pragma unroll
        for (int r = 0; r < 4; ++r)
            ht[wv * 16 + quad * 4 + r][nt * 16 + l15] = f2bf(acc1[nt][r] + bnv);
    }
    __syncthreads();

    floatx4 acc2a[4] = {}, acc2c[4] = {};
    #pragma unroll
    for (int ks = 0; ks < 2; ++ks) {
        short8 a = *(const short8*)&ht[wv * 16 + l15][ks * 32 + quad * 8];
        #pragma unroll
        for (int ft = 0; ft < 4; ++ft) {
            short8 ba = *(const short8*)&w1at[ft * 16 + l15][ks * 32 + quad * 8];
            short8 bb = *(const short8*)&w1bt[ft * 16 + l15][ks * 32 + quad * 8];
            acc2a[ft] = __builtin_amdgcn_mfma_f32_16x16x32_bf16(a, ba, acc2a[ft], 0, 0, 0);
            acc2c[ft] = __builtin_amdgcn_mfma_f32_16x16x32_bf16(a, bb, acc2c[ft], 0, 0, 0);
        }
    }

    #pragma unroll
    for (int ft = 0; ft < 4; ++ft) {
        float b1v = b1[ft * 16 + l15];
        #pragma unroll
        for (int r = 0; r < 4; ++r) {
            int m = wv * 16 + quad * 4 + r;
            size_t idx = (size_t)(m0 + m) * 4096 + n0 + ft * 16 + l15;
            a_ws[idx] = __float2bfloat16(acc2a[ft][r] + b1v);
            c_ws[idx] = __float2bfloat16(acc2c[ft][r]);
        }
    }
}

// -------------------------------------------------------------------------
// Kernel 2 (R7 config, known good): pairwise relu + W2 contraction + mask +
// symmetrize. Grid 512 = (batch, half): block owns 32 i-rows, wave owns ONE
// 8-row octet (keeps the worst block at 1 compute-octet/wave — R8's
// 2-octets/wave doubled the makespan; do not merge). fp32 LDS + float2
// packed math (v_pk_add_f32 / v_pk_fma_f32): VALU is the binding pipe.
// -------------------------------------------------------------------------
__global__ __launch_bounds__(256) void k_pairs(
    const bf16* __restrict__ a_ws, const bf16* __restrict__ c_ws,
    const int* __restrict__ nra, const float* __restrict__ W2,
    const float* __restrict__ b2, float* __restrict__ out)
{
    __shared__ __align__(16) float as[64][68];
    __shared__ __align__(16) float cs[64][68];
    __shared__ __align__(16) float w2t[5][68];

    const int t = threadIdx.x;
    const int b = blockIdx.x >> 1;
    const int ic = blockIdx.x & 1;
    const int n = nra[b];

    #pragma unroll
    for (int r = 0; r < 4; ++r) {                 // bf16 ws -> fp32 LDS
        int q = t + 256 * r;
        int atom = q >> 4, ff = (q & 15) * 4;
        ushort4 av = *(const ushort4*)((const ushort*)a_ws + (size_t)b * 4096 + 4 * q);
        ushort4 cv = *(const ushort4*)((const ushort*)c_ws + (size_t)b * 4096 + 4 * q);
        as[atom][ff + 0] = b2f(__ushort_as_bfloat16(av.x));
        as[atom][ff + 1] = b2f(__ushort_as_bfloat16(av.y));
        as[atom][ff + 2] = b2f(__ushort_as_bfloat16(av.z));
        as[atom][ff + 3] = b2f(__ushort_as_bfloat16(av.w));
        cs[atom][ff + 0] = b2f(__ushort_as_bfloat16(cv.x));
        cs[atom][ff + 1] = b2f(__ushort_as_bfloat16(cv.y));
        cs[atom][ff + 2] = b2f(__ushort_as_bfloat16(cv.z));
        cs[atom][ff + 3] = b2f(__ushort_as_bfloat16(cv.w));
    }
    if (t < 64) {
        #pragma unroll
        for (int k = 0; k < 5; ++k) w2t[k][t] = W2[t * 5 + k];
    }
    float b2v[5];
    #pragma unroll
    for (int k = 0; k < 5; ++k) b2v[k] = b2[k];
    __syncthreads();

    const int j = t & 63;
    const int wv = t >> 6;
    const int i0 = ic * 32 + wv * 8;              // this wave's 8 rows
    const float fillv[5] = {-HUGEF, -HUGEF, -HUGEF, -HUGEF, HUGEF};

    if (i0 >= n) {                                 // all 8 rows padding
        #pragma unroll
        for (int r = 0; r < 8; ++r) {
            float* op = out + ((size_t)(b * 64 + i0 + r) * 64 + j) * 5;
            #pragma unroll
            for (int k = 0; k < 5; ++k) op[k] = fillv[k];
        }
        return;
    }

    float2v acc2[8][5] = {};                       // pairwise accumulators
    for (int w8 = 0; w8 < 8; ++w8) {               // 8 f per iter
        const int f0 = w8 * 8;
        float4 ajA = *(const float4*)&as[j][f0];
        float4 ajB = *(const float4*)&as[j][f0 + 4];
        float4 cjA = *(const float4*)&cs[j][f0];
        float4 cjB = *(const float4*)&cs[j][f0 + 4];
        float2v aj0 = mk2(ajA.x, ajA.y), aj1 = mk2(ajA.z, ajA.w);
        float2v aj2 = mk2(ajB.x, ajB.y), aj3 = mk2(ajB.z, ajB.w);
        float2v cj0 = mk2(cjA.x, cjA.y), cj1 = mk2(cjA.z, cjA.w);
        float2v cj2 = mk2(cjB.x, cjB.y), cj3 = mk2(cjB.z, cjB.w);
        float2v w[5][4];
        #pragma unroll
        for (int k = 0; k < 5; ++k) {
            float4 wA = *(const float4*)&w2t[k][f0];
            float4 wB = *(const float4*)&w2t[k][f0 + 4];
            w[k][0] = mk2(wA.x, wA.y); w[k][1] = mk2(wA.z, wA.w);
            w[k][2] = mk2(wB.x, wB.y); w[k][3] = mk2(wB.z, wB.w);
        }
        #pragma unroll
        for (int r = 0; r < 8; ++r) {
            float4 aiA = *(const float4*)&as[i0 + r][f0];     // broadcast
            float4 aiB = *(const float4*)&as[i0 + r][f0 + 4];
            float4 ciA = *(const float4*)&cs[i0 + r][f0];
            float4 ciB = *(const float4*)&cs[i0 + r][f0 + 4];
            float2v s0 = relu2(mk2(aiA.x, aiA.y) + cj0) + relu2(aj0 + mk2(ciA.x, ciA.y));
            float2v s1 = relu2(mk2(aiA.z, aiA.w) + cj1) + relu2(aj1 + mk2(ciA.z, ciA.w));
            float2v s2 = relu2(mk2(aiB.x, aiB.y) + cj2) + relu2(aj2 + mk2(ciB.x, ciB.y));
            float2v s3 = relu2(mk2(aiB.z, aiB.w) + cj3) + relu2(aj3 + mk2(ciB.z, ciB.w));
            #pragma unroll
            for (int k = 0; k < 5; ++k)
                acc2[r][k] += s0 * w[k][0] + s1 * w[k][1] +
                              s2 * w[k][2] + s3 * w[k][3];
        }
    }

    #pragma unroll
    for (int r = 0; r < 8; ++r) {
        const int i = i0 + r;
        float* op = out + ((size_t)(b * 64 + i) * 64 + j) * 5;
        if (i >= n) {
            #pragma unroll
            for (int k = 0; k < 5; ++k) op[k] = fillv[k];
        } else {
            const bool masked = (j == i) || (j >= n);
            #pragma unroll
            for (int k = 0; k < 5; ++k) {
                float v = masked ? fillv[k]
                                 : (0.5f * (acc2[r][k].x + acc2[r][k].y) + b2v[k]);
                op[k] = v;
            }
        }
    }
}

extern "C" void kernel_launch(void* const* d_in, const int* in_sizes, int n_in,
                              void* d_out, int out_size, void* d_ws, size_t ws_size,
                              hipStream_t stream)
{
    const float* z  = (const float*)d_in[0];   // (256, 256) fp32
    const int*   nra = (const int*)d_in[1];    // (256,) int32
    const float* Wn = (const float*)d_in[2];   // (256, 4096) fp32
    const float* bn = (const float*)d_in[3];   // (4096,) fp32
    const float* W1 = (const float*)d_in[4];   // (128, 64) fp32
    const float* b1 = (const float*)d_in[5];   // (64,) fp32
    const float* W2 = (const float*)d_in[6];   // (64, 5) fp32
    const float* b2 = (const float*)d_in[7];   // (5,) fp32
    float* out = (float*)d_out;                // (256, 64, 64, 5) fp32

    bf16* a_ws = (bf16*)d_ws;                  // 256*4096 bf16 (a' = a + b1)
    bf16* c_ws = a_ws + 256 * 4096;            // 256*4096 bf16

    hipLaunchKernelGGL(k_hac, dim3(64, 4), dim3(256), 0, stream,
                       z, Wn, bn, W1, b1, a_ws, c_ws);
    hipLaunchKernelGGL(k_pairs, dim3(512), dim3(256), 0, stream,
                       a_ws, c_ws, nra, W2, b2, out);
}